// Round 16
// baseline (330.877 us; speedup 1.0000x reference)
//
#include <hip/hip_runtime.h>
#include <hip/hip_fp16.h>

#define H 64
#define BSHIFT 9
#define BUCKET 512
#define NBMAX 256
#define CHUNK 4096

__device__ __forceinline__ int bcasti(int x, int j) {
    return __builtin_amdgcn_readlane(x, j);
}
__device__ __forceinline__ float bcastf(float x, int j) {
    return __uint_as_float((unsigned)__builtin_amdgcn_readlane((int)__float_as_uint(x), j));
}

__device__ __forceinline__ float ldf(const float* p) { return *p; }
__device__ __forceinline__ float ldf(const __half* p) { return __half2float(*p); }

// v2all[b][k] = sum_j Wd_b[k][j] * ad_b[j]  for the 3 used relations
__global__ void wvec3_kernel(const float* __restrict__ W_dst, const float* __restrict__ att_dst,
                             float* __restrict__ v2all) {
    int b = blockIdx.x;
    int k = threadIdx.x;
    const float* Wd = W_dst + (size_t)b * H * H;
    const float* ad = att_dst + (size_t)b * H;
    float s2 = 0.f;
    for (int j = 0; j < H; ++j) s2 += Wd[k * H + j] * ad[j];
    v2all[b * H + k] = s2;
}

// ---- proj device body: 16 rows/block, 4 rows/wave (templated input type) ----
template <typename T>
__device__ __forceinline__ void proj_body(float* __restrict__ Wl, int blk,
                                          const T* __restrict__ x, const float* __restrict__ W,
                                          const float* __restrict__ as_, const float* __restrict__ v2d,
                                          __half* __restrict__ hs, float* __restrict__ ssrc,
                                          float* __restrict__ sdst_out, int n) {
    int t = threadIdx.x;
    for (int i = t; i < H * H; i += 256) Wl[i] = W[i];
    __syncthreads();
    int lane = t & 63;
    int w = t >> 6;
    int row0 = blk * 16 + w * 4;
    if (row0 >= n) return;
    int rem = n - row0;
    float asl = as_[lane];
    const T* xp = x + (size_t)row0 * H + lane;
    float xr0 = ldf(xp);
    float xr1 = rem > 1 ? ldf(xp + H) : 0.f;
    float xr2 = rem > 2 ? ldf(xp + 2 * H) : 0.f;
    float xr3 = rem > 3 ? ldf(xp + 3 * H) : 0.f;
    float a0 = 0.f, a1 = 0.f, a2 = 0.f, a3 = 0.f;
#pragma unroll
    for (int k = 0; k < H; ++k) {
        float wv = Wl[k * H + lane];
        a0 = fmaf(bcastf(xr0, k), wv, a0);
        a1 = fmaf(bcastf(xr1, k), wv, a1);
        a2 = fmaf(bcastf(xr2, k), wv, a2);
        a3 = fmaf(bcastf(xr3, k), wv, a3);
    }
    __half* hp = hs + (size_t)row0 * H + lane;
    hp[0] = __float2half_rn(a0);
    if (rem > 1) hp[H] = __float2half_rn(a1);
    if (rem > 2) hp[2 * H] = __float2half_rn(a2);
    if (rem > 3) hp[3 * H] = __float2half_rn(a3);
    float p0 = a0 * asl, p1 = a1 * asl, p2 = a2 * asl, p3 = a3 * asl;
#pragma unroll
    for (int off = 32; off; off >>= 1) {
        p0 += __shfl_xor(p0, off); p1 += __shfl_xor(p1, off);
        p2 += __shfl_xor(p2, off); p3 += __shfl_xor(p3, off);
    }
    if (lane == 0) {
        ssrc[row0] = p0;
        if (rem > 1) ssrc[row0 + 1] = p1;
        if (rem > 2) ssrc[row0 + 2] = p2;
        if (rem > 3) ssrc[row0 + 3] = p3;
    }
    if (sdst_out) {
        float vl = v2d[lane];
        float q0 = xr0 * vl, q1 = xr1 * vl, q2 = xr2 * vl, q3 = xr3 * vl;
#pragma unroll
        for (int off = 32; off; off >>= 1) {
            q0 += __shfl_xor(q0, off); q1 += __shfl_xor(q1, off);
            q2 += __shfl_xor(q2, off); q3 += __shfl_xor(q3, off);
        }
        if (lane == 0) {
            sdst_out[row0] = q0;
            if (rem > 1) sdst_out[row0 + 1] = q1;
            if (rem > 2) sdst_out[row0 + 2] = q2;
            if (rem > 3) sdst_out[row0 + 3] = q3;
        }
    }
}

// ---- fused: part_hist || proj0 ----
__global__ void hist_proj_kernel(const int* __restrict__ dstA, const int* __restrict__ dstB,
                                 int* __restrict__ cntA, int* __restrict__ cntB,
                                 int ne, int nch, int nbA, int nbB,
                                 const float* __restrict__ x, const float* __restrict__ W,
                                 const float* __restrict__ as_, const float* __restrict__ v2d,
                                 __half* __restrict__ hs, float* __restrict__ ssrc,
                                 float* __restrict__ sdst_out, int n) {
    __shared__ float smem[H * H];
    int blk = blockIdx.x;
    if (blk < 2 * nch) {
        int* h = (int*)smem;
        bool second = blk >= nch;
        const int* dst = second ? dstB : dstA;
        int* cnt = second ? cntB : cntA;
        int nb = second ? nbB : nbA;
        int c = second ? blk - nch : blk;
        int beg = c * CHUNK, end = beg + CHUNK;
        if (end > ne) end = ne;
        int t = threadIdx.x;
        for (int i = t; i < NBMAX; i += 256) h[i] = 0;
        __syncthreads();
        for (int i = beg + t; i < end; i += 256) atomicAdd(&h[dst[i] >> BSHIFT], 1);
        __syncthreads();
        for (int b = t; b < nb; b += 256) cnt[(size_t)b * nch + c] = h[b];
        return;
    }
    proj_body<float>(smem, blk - 2 * nch, x, W, as_, v2d, hs, ssrc, sdst_out, n);
}

__global__ void scan_chunks(int* __restrict__ cntA, int* __restrict__ cntB,
                            int* __restrict__ totA, int* __restrict__ totB,
                            int nch, int nbA) {
    __shared__ int sm[512];
    int b = blockIdx.x;
    bool second = b >= nbA;
    int* cnt = second ? cntB : cntA;
    int* tot = second ? totB : totA;
    if (second) b -= nbA;
    int t = threadIdx.x;
    int v = t < nch ? cnt[(size_t)b * nch + t] : 0;
    sm[t] = v;
    __syncthreads();
    for (int off = 1; off < 512; off <<= 1) {
        int u = t >= off ? sm[t - off] : 0;
        __syncthreads();
        sm[t] += u;
        __syncthreads();
    }
    if (t < nch) cnt[(size_t)b * nch + t] = sm[t] - v;
    if (t == 511) tot[b] = sm[511];
}

__global__ void scan_buckets(const int* __restrict__ totA, const int* __restrict__ totB,
                             int* __restrict__ bstartA, int* __restrict__ bstartB,
                             int nbA, int nbB, int ne) {
    __shared__ int sm[256];
    const int* tot = blockIdx.x ? totB : totA;
    int* bstart = blockIdx.x ? bstartB : bstartA;
    int nb = blockIdx.x ? nbB : nbA;
    int t = threadIdx.x;
    int v = t < nb ? tot[t] : 0;
    sm[t] = v;
    __syncthreads();
    for (int off = 1; off < 256; off <<= 1) {
        int u = t >= off ? sm[t - off] : 0;
        __syncthreads();
        sm[t] += u;
        __syncthreads();
    }
    if (t < nb) bstart[t] = sm[t] - v;
    if (t == 0) bstart[nb] = ne;
}

// ---- fused: part_scatter || proj1 ----
__global__ void scatter_proj_kernel(const int* __restrict__ srcA, const int* __restrict__ dstA,
                                    const int* __restrict__ cntA, const int* __restrict__ bstartA,
                                    unsigned* __restrict__ tmpA,
                                    const int* __restrict__ srcB, const int* __restrict__ dstB,
                                    const int* __restrict__ cntB, const int* __restrict__ bstartB,
                                    unsigned* __restrict__ tmpB,
                                    int ne, int nch, int nbA, int nbB,
                                    const float* __restrict__ x, const float* __restrict__ W,
                                    const float* __restrict__ as_, const float* __restrict__ v2d,
                                    __half* __restrict__ hs, float* __restrict__ ssrc,
                                    float* __restrict__ sdst_out, int n) {
    __shared__ float smem[H * H];
    int blk = blockIdx.x;
    if (blk < 2 * nch) {
        int* cur = (int*)smem;
        bool second = blk >= nch;
        const int* src = second ? srcB : srcA;
        const int* dst = second ? dstB : dstA;
        const int* cnt = second ? cntB : cntA;
        const int* bstart = second ? bstartB : bstartA;
        unsigned* tmp = second ? tmpB : tmpA;
        int nb = second ? nbB : nbA;
        int c = second ? blk - nch : blk;
        int beg = c * CHUNK, end = beg + CHUNK;
        if (end > ne) end = ne;
        int t = threadIdx.x;
        for (int b = t; b < nb; b += 256) cur[b] = bstart[b] + cnt[(size_t)b * nch + c];
        __syncthreads();
        for (int i = beg + t; i < end; i += 256) {
            int d = dst[i];
            int pos = atomicAdd(&cur[d >> BSHIFT], 1);
            unsigned rec = ((unsigned)(d & (BUCKET - 1)) << 17) | (unsigned)src[i];
            tmp[pos] = rec;
        }
        return;
    }
    proj_body<float>(smem, blk - 2 * nch, x, W, as_, v2d, hs, ssrc, sdst_out, n);
}

__global__ void bucket_finalize(const unsigned* __restrict__ tmpA, const int* __restrict__ bstartA,
                                int* __restrict__ rowptrA, int* __restrict__ srcsA,
                                int ndstA, int nbA,
                                const unsigned* __restrict__ tmpB, const int* __restrict__ bstartB,
                                int* __restrict__ rowptrB, int* __restrict__ srcsB,
                                int ndstB) {
    __shared__ int cnt[BUCKET];
    __shared__ int sm[BUCKET];
    __shared__ int cur[BUCKET];
    int b = blockIdx.x;
    bool second = b >= nbA;
    const unsigned* tmp = second ? tmpB : tmpA;
    const int* bstart = second ? bstartB : bstartA;
    int* rowptr = second ? rowptrB : rowptrA;
    int* srcs   = second ? srcsB : srcsA;
    int ndst    = second ? ndstB : ndstA;
    if (second) b -= nbA;

    int t = threadIdx.x;
    int base = bstart[b], endi = bstart[b + 1];
    cnt[t] = 0;
    __syncthreads();
    for (int i = base + t; i < endi; i += 512)
        atomicAdd(&cnt[tmp[i] >> 17], 1);
    __syncthreads();
    int c0 = cnt[t];
    sm[t] = c0;
    __syncthreads();
    for (int off = 1; off < 512; off <<= 1) {
        int u = t >= off ? sm[t - off] : 0;
        __syncthreads();
        sm[t] += u;
        __syncthreads();
    }
    int d0 = b << BSHIFT;
    int e = base + sm[t] - c0;
    cur[t] = e;
    if (d0 + t < ndst) rowptr[d0 + t] = e;
    if (t == 0) {
        int hi = d0 + BUCKET;
        if (hi > ndst) hi = ndst;
        rowptr[hi] = endi;
    }
    __syncthreads();
    for (int i = base + t; i < endi; i += 512) {
        unsigned rec = tmp[i];
        int pos = atomicAdd(&cur[rec >> 17], 1);
        srcs[pos] = (int)(rec & 0x1FFFFu);
    }
}

// ---- tiered fast path: P in {16, 32}; wave-uniform branch, no divergence ----
template <int P>
__device__ __forceinline__ float gat_fast(const int* __restrict__ srcs, int beg, int cnt,
                                          const float* __restrict__ ssrc, float sdst,
                                          const __half* __restrict__ hs,
                                          const float* __restrict__ bias, int lane) {
    bool valid = lane < cnt;
    int s_l = valid ? srcs[beg + lane] : 0;
    float ss = valid ? ssrc[s_l] : 0.f;

    const __half* hsl = hs + lane;
    __half hv[P];
#pragma unroll
    for (int k = 0; k < P; ++k) {
        hv[k] = hsl[(size_t)bcasti(s_l, k) * H];
    }

    float sc = ss + sdst;
    sc = sc > 0.f ? sc : 0.2f * sc;
    float ev_l = valid ? __expf(sc) : 0.f;
    float ll = ev_l;
#pragma unroll
    for (int off = 32; off; off >>= 1) ll += __shfl_xor(ll, off);

    float acc0 = 0.f, acc1 = 0.f, acc2 = 0.f, acc3 = 0.f;
    float acc4 = 0.f, acc5 = 0.f, acc6 = 0.f, acc7 = 0.f;
#pragma unroll
    for (int k = 0; k < P; k += 8) {
        acc0 += bcastf(ev_l, k + 0) * __half2float(hv[k + 0]);
        acc1 += bcastf(ev_l, k + 1) * __half2float(hv[k + 1]);
        acc2 += bcastf(ev_l, k + 2) * __half2float(hv[k + 2]);
        acc3 += bcastf(ev_l, k + 3) * __half2float(hv[k + 3]);
        acc4 += bcastf(ev_l, k + 4) * __half2float(hv[k + 4]);
        acc5 += bcastf(ev_l, k + 5) * __half2float(hv[k + 5]);
        acc6 += bcastf(ev_l, k + 6) * __half2float(hv[k + 6]);
        acc7 += bcastf(ev_l, k + 7) * __half2float(hv[k + 7]);
    }
    if constexpr (P == 32) {
        // tail for 32 < cnt <= 64
        int j = P;
        for (; j + 3 < cnt; j += 4) {
            acc0 += bcastf(ev_l, j + 0) * __half2float(hsl[(size_t)bcasti(s_l, j + 0) * H]);
            acc1 += bcastf(ev_l, j + 1) * __half2float(hsl[(size_t)bcasti(s_l, j + 1) * H]);
            acc2 += bcastf(ev_l, j + 2) * __half2float(hsl[(size_t)bcasti(s_l, j + 2) * H]);
            acc3 += bcastf(ev_l, j + 3) * __half2float(hsl[(size_t)bcasti(s_l, j + 3) * H]);
        }
        for (; j < cnt; ++j)
            acc0 += bcastf(ev_l, j) * __half2float(hsl[(size_t)bcasti(s_l, j) * H]);
    }
    float v = ((acc0 + acc1) + (acc2 + acc3)) + ((acc4 + acc5) + (acc6 + acc7));
    v = v / (ll + 1e-16f) + bias[lane];
    return v > 0.f ? v : 0.f;
}

// general path (cnt > 64) + tier dispatch
__device__ __forceinline__ float gat_aggregate(const int* __restrict__ rowptr,
                                               const int* __restrict__ srcs,
                                               const float* __restrict__ ssrc,
                                               float sdst,
                                               const __half* __restrict__ hs,
                                               const float* __restrict__ bias,
                                               int wid, int lane) {
    int beg = rowptr[wid], end = rowptr[wid + 1];
    int cnt = end - beg;
    if (cnt <= 16) return gat_fast<16>(srcs, beg, cnt, ssrc, sdst, hs, bias, lane);
    if (cnt <= 64) return gat_fast<32>(srcs, beg, cnt, ssrc, sdst, hs, bias, lane);

    const __half* hsl = hs + lane;
    float acc0 = 0.f, acc1 = 0.f;
    float mm = -3.4e38f;
    for (int base = beg; base < end; base += 64) {
        int idx = base + lane;
        if (idx < end) {
            float sc = ssrc[srcs[idx]] + sdst;
            sc = sc > 0.f ? sc : 0.2f * sc;
            mm = fmaxf(mm, sc);
        }
    }
#pragma unroll
    for (int off = 32; off; off >>= 1) mm = fmaxf(mm, __shfl_xor(mm, off));
    float ll = 0.f;
    for (int base = beg; base < end; base += 64) {
        int idx = base + lane;
        int c2 = end - base; if (c2 > 64) c2 = 64;
        int s_l = idx < end ? srcs[idx] : 0;
        float ev_l = 0.f;
        if (idx < end) {
            float sc = ssrc[s_l] + sdst;
            sc = sc > 0.f ? sc : 0.2f * sc;
            ev_l = __expf(sc - mm);
        }
        ll += ev_l;
        int j = 0;
        for (; j + 1 < c2; j += 2) {
            acc0 += bcastf(ev_l, j) * __half2float(hsl[(size_t)bcasti(s_l, j) * H]);
            acc1 += bcastf(ev_l, j + 1) * __half2float(hsl[(size_t)bcasti(s_l, j + 1) * H]);
        }
        if (j < c2)
            acc0 += bcastf(ev_l, j) * __half2float(hsl[(size_t)bcasti(s_l, j) * H]);
    }
#pragma unroll
    for (int off = 32; off; off >>= 1) ll += __shfl_xor(ll, off);
    float v = (acc0 + acc1) / (ll + 1e-16f) + bias[lane];
    return v > 0.f ? v : 0.f;
}

// gat1 alone (critical path): rel1 -> fp16 xiA
__global__ void gat1_kernel(const int* __restrict__ rp1, const int* __restrict__ sr1,
                            const float* __restrict__ ssrc1, const float* __restrict__ sdst1,
                            const __half* __restrict__ hs1, const float* __restrict__ bias1,
                            __half* __restrict__ out1, int n1) {
    int wid = (int)((blockIdx.x * blockDim.x + threadIdx.x) >> 6);
    int lane = threadIdx.x & 63;
    if (wid >= n1) return;
    float v = gat_aggregate(rp1, sr1, ssrc1, sdst1[wid], hs1, bias1, wid, lane);
    out1[(size_t)wid * H + lane] = __float2half_rn(v);
}

// fused: gat0 (sdst-only, rel0) || proj2 (fp16 xiA -> hs2/ssrc2)
__global__ void gat0_proj_kernel(const int* __restrict__ rp0, const int* __restrict__ sr0,
                                 const float* __restrict__ ssrc0, const float* __restrict__ sdst0,
                                 const __half* __restrict__ hs0, const float* __restrict__ bias0,
                                 const float* __restrict__ v2next, float* __restrict__ sdstNext, int n0,
                                 const __half* __restrict__ xiA, const float* __restrict__ Wsrc2,
                                 const float* __restrict__ as2,
                                 __half* __restrict__ hs2, float* __restrict__ ssrc2, int n1) {
    __shared__ float smem[H * H];
    int nblk0 = (n0 + 3) / 4;
    if ((int)blockIdx.x < nblk0) {
        int wid = (int)((blockIdx.x * blockDim.x + threadIdx.x) >> 6);
        int lane = threadIdx.x & 63;
        if (wid >= n0) return;
        float v = gat_aggregate(rp0, sr0, ssrc0, sdst0[wid], hs0, bias0, wid, lane);
        float q = v * v2next[lane];
#pragma unroll
        for (int off = 32; off; off >>= 1) q += __shfl_xor(q, off);
        if (lane == 0) sdstNext[wid] = q;
        return;
    }
    proj_body<__half>(smem, blockIdx.x - nblk0, xiA, Wsrc2, as2, nullptr, hs2, ssrc2, nullptr, n1);
}

// final relation: GAT aggregation + fused MLP head
__global__ void gat_node_mlp_kernel(const int* __restrict__ rowptr, const int* __restrict__ srcs,
                                    const float* __restrict__ ssrc, const float* __restrict__ sdstArr,
                                    const __half* __restrict__ hs, const float* __restrict__ bias,
                                    const float* __restrict__ w1, const float* __restrict__ b1,
                                    const float* __restrict__ w2, const float* __restrict__ b2,
                                    float* __restrict__ out, int ndst) {
    __shared__ float W1[H * 32];
    __shared__ float W2[32];
    __shared__ float B1[32];
    {
        int t = threadIdx.x;
        for (int i = t; i < H * 32; i += 256) W1[i] = w1[i];
        if (t < 32) { W2[t] = w2[t]; B1[t] = b1[t]; }
        __syncthreads();
    }
    int wid = (int)((blockIdx.x * blockDim.x + threadIdx.x) >> 6);
    int lane = threadIdx.x & 63;
    if (wid >= ndst) return;
    float v = gat_aggregate(rowptr, srcs, ssrc, sdstArr[wid], hs, bias, wid, lane);

    int c = lane & 31;
    int kbase = (lane >> 5) << 5;
    float s = 0.f;
#pragma unroll
    for (int k = 0; k < 32; ++k) s += __shfl(v, kbase + k) * W1[(kbase + k) * 32 + c];
    s += __shfl_xor(s, 32);
    s += B1[c];
    s = s > 0.f ? s : 0.f;
    float q = s * W2[c];
#pragma unroll
    for (int off = 16; off; off >>= 1) q += __shfl_xor(q, off);
    if (lane == 0) out[wid] = q + b2[0];
}

extern "C" void kernel_launch(void* const* d_in, const int* in_sizes, int n_in,
                              void* d_out, int out_size, void* d_ws, size_t ws_size,
                              hipStream_t stream) {
    const float* x_inst  = (const float*)d_in[0];
    const float* x_net   = (const float*)d_in[1];
    const int*   e_i2n   = (const int*)d_in[2];
    const int*   e_n2i   = (const int*)d_in[3];
    const float* W_src   = (const float*)d_in[4];
    const float* W_dst   = (const float*)d_in[5];
    const float* att_src = (const float*)d_in[6];
    const float* att_dst = (const float*)d_in[7];
    const float* bias_g  = (const float*)d_in[8];
    const float* lin1_w  = (const float*)d_in[9];
    const float* lin1_b  = (const float*)d_in[10];
    const float* lin2_w  = (const float*)d_in[11];
    const float* lin2_b  = (const float*)d_in[12];

    const int n_inst = in_sizes[0] / H;
    const int n_net  = in_sizes[1] / H;
    const int ne     = in_sizes[2] / 2;
    const int nmax   = n_inst > n_net ? n_inst : n_net;

    const int nbA = (n_net + BUCKET - 1) >> BSHIFT;
    const int nbB = (n_inst + BUCKET - 1) >> BSHIFT;
    const int nch = (ne + CHUNK - 1) / CHUNK;   // must be <= 512

    float* ws = (float*)d_ws;
    size_t off = 0;
    auto alloc = [&](size_t nelem) {
        off = (off + 3) & ~(size_t)3;
        float* p = ws + off; off += nelem; return p;
    };
    __half* xiA    = (__half*)alloc((size_t)n_inst * H / 2);
    __half* hs0    = (__half*)alloc((size_t)nmax * H / 2);
    __half* hs1    = (__half*)alloc((size_t)nmax * H / 2);
    __half* hs2    = (__half*)alloc((size_t)nmax * H / 2);
    float* ssrc0   = alloc(nmax);
    float* ssrc1   = alloc(nmax);
    float* ssrc2   = alloc(nmax);
    float* sdstA   = alloc(nmax);
    float* sdstB   = alloc(nmax);
    float* sdstC   = alloc(nmax);
    int*   rp_i2n  = (int*)alloc(nmax + 1);
    int*   sr_i2n  = (int*)alloc(ne);
    int*   rp_n2i  = (int*)alloc(nmax + 1);
    int*   sr_n2i  = (int*)alloc(ne);
    unsigned* tmpA = (unsigned*)alloc(ne);
    unsigned* tmpB = (unsigned*)alloc(ne);
    int*   cntA    = (int*)alloc((size_t)NBMAX * nch);
    int*   cntB    = (int*)alloc((size_t)NBMAX * nch);
    int*   totA    = (int*)alloc(NBMAX);
    int*   totB    = (int*)alloc(NBMAX);
    int*   bstartA = (int*)alloc(NBMAX + 1);
    int*   bstartB = (int*)alloc(NBMAX + 1);
    float* v2all   = alloc(3 * H);
    (void)ws_size;

    const int* dstA = e_i2n + ne;   // dst = net
    const int* dstB = e_n2i + ne;   // dst = inst

    wvec3_kernel<<<3, 64, 0, stream>>>(W_dst, att_dst, v2all);

    // hist (A+B) || proj0: x_inst -> hs0/ssrc0; sdstB = x_inst . v2[rel1]
    {
        int grid = 2 * nch + (n_inst + 15) / 16;
        hist_proj_kernel<<<grid, 256, 0, stream>>>(dstA, dstB, cntA, cntB, ne, nch, nbA, nbB,
                                                   x_inst, W_src + 0 * H * H, att_src + 0 * H,
                                                   v2all + 1 * H, hs0, ssrc0, sdstB, n_inst);
    }
    scan_chunks<<<nbA + nbB, 512, 0, stream>>>(cntA, cntB, totA, totB, nch, nbA);
    scan_buckets<<<2, 256, 0, stream>>>(totA, totB, bstartA, bstartB, nbA, nbB, ne);
    // scatter (A+B) || proj1: x_net -> hs1/ssrc1; sdstA = x_net . v2[rel0]
    {
        int grid = 2 * nch + (n_net + 15) / 16;
        scatter_proj_kernel<<<grid, 256, 0, stream>>>(e_i2n, dstA, cntA, bstartA, tmpA,
                                                      e_n2i, dstB, cntB, bstartB, tmpB,
                                                      ne, nch, nbA, nbB,
                                                      x_net, W_src + 1 * H * H, att_src + 1 * H,
                                                      v2all + 0 * H, hs1, ssrc1, sdstA, n_net);
    }
    bucket_finalize<<<nbA + nbB, 512, 0, stream>>>(tmpA, bstartA, rp_i2n, sr_i2n, n_net, nbA,
                                                   tmpB, bstartB, rp_n2i, sr_n2i, n_inst);

    // gat1 (rel1 -> fp16 xiA): critical path first
    gat1_kernel<<<(n_inst + 3) / 4, 256, 0, stream>>>(rp_n2i, sr_n2i, ssrc1, sdstB,
                                                      hs1, bias_g + 1 * H, xiA, n_inst);
    // gat0 (rel0, sdst-only -> sdstC) || proj2 (fp16 xiA -> hs2/ssrc2)
    {
        int grid = (n_net + 3) / 4 + (n_inst + 15) / 16;
        gat0_proj_kernel<<<grid, 256, 0, stream>>>(rp_i2n, sr_i2n, ssrc0, sdstA, hs0,
                                                   bias_g + 0 * H, v2all + 2 * H, sdstC, n_net,
                                                   xiA, W_src + 2 * H * H, att_src + 2 * H,
                                                   hs2, ssrc2, n_inst);
    }
    // gat2 (rel2) + MLP head -> d_out
    gat_node_mlp_kernel<<<(n_net + 3) / 4, 256, 0, stream>>>(rp_i2n, sr_i2n, ssrc2, sdstC,
                                                             hs2, bias_g + 2 * H,
                                                             lin1_w, lin1_b, lin2_w, lin2_b,
                                                             (float*)d_out, n_net);
}

// Round 17
// 327.896 us; speedup vs baseline: 1.0091x; 1.0091x over previous
//
#include <hip/hip_runtime.h>
#include <hip/hip_fp16.h>

#define H 64
#define BSHIFT 9
#define BUCKET 512
#define NBMAX 256
#define CHUNK 4096

__device__ __forceinline__ int bcasti(int x, int j) {
    return __builtin_amdgcn_readlane(x, j);
}
__device__ __forceinline__ float bcastf(float x, int j) {
    return __uint_as_float((unsigned)__builtin_amdgcn_readlane((int)__float_as_uint(x), j));
}

__device__ __forceinline__ float ldf(const float* p) { return *p; }
__device__ __forceinline__ float ldf(const __half* p) { return __half2float(*p); }

// v2all[b][k] = sum_j Wd_b[k][j] * ad_b[j]
__global__ void wvec3_kernel(const float* __restrict__ W_dst, const float* __restrict__ att_dst,
                             float* __restrict__ v2all) {
    int b = blockIdx.x;
    int k = threadIdx.x;
    const float* Wd = W_dst + (size_t)b * H * H;
    const float* ad = att_dst + (size_t)b * H;
    float s2 = 0.f;
    for (int j = 0; j < H; ++j) s2 += Wd[k * H + j] * ad[j];
    v2all[b * H + k] = s2;
}

// ---- proj device body: 16 rows/block, 4 rows/wave ----
template <typename T>
__device__ __forceinline__ void proj_body(float* __restrict__ Wl, int blk,
                                          const T* __restrict__ x, const float* __restrict__ W,
                                          const float* __restrict__ as_, const float* __restrict__ v2d,
                                          __half* __restrict__ hs, float* __restrict__ ssrc,
                                          float* __restrict__ sdst_out, int n) {
    int t = threadIdx.x;
    for (int i = t; i < H * H; i += 256) Wl[i] = W[i];
    __syncthreads();
    int lane = t & 63;
    int w = t >> 6;
    int row0 = blk * 16 + w * 4;
    if (row0 >= n) return;
    int rem = n - row0;
    float asl = as_[lane];
    const T* xp = x + (size_t)row0 * H + lane;
    float xr0 = ldf(xp);
    float xr1 = rem > 1 ? ldf(xp + H) : 0.f;
    float xr2 = rem > 2 ? ldf(xp + 2 * H) : 0.f;
    float xr3 = rem > 3 ? ldf(xp + 3 * H) : 0.f;
    float a0 = 0.f, a1 = 0.f, a2 = 0.f, a3 = 0.f;
#pragma unroll
    for (int k = 0; k < H; ++k) {
        float wv = Wl[k * H + lane];
        a0 = fmaf(bcastf(xr0, k), wv, a0);
        a1 = fmaf(bcastf(xr1, k), wv, a1);
        a2 = fmaf(bcastf(xr2, k), wv, a2);
        a3 = fmaf(bcastf(xr3, k), wv, a3);
    }
    __half* hp = hs + (size_t)row0 * H + lane;
    hp[0] = __float2half_rn(a0);
    if (rem > 1) hp[H] = __float2half_rn(a1);
    if (rem > 2) hp[2 * H] = __float2half_rn(a2);
    if (rem > 3) hp[3 * H] = __float2half_rn(a3);
    float p0 = a0 * asl, p1 = a1 * asl, p2 = a2 * asl, p3 = a3 * asl;
#pragma unroll
    for (int off = 32; off; off >>= 1) {
        p0 += __shfl_xor(p0, off); p1 += __shfl_xor(p1, off);
        p2 += __shfl_xor(p2, off); p3 += __shfl_xor(p3, off);
    }
    if (lane == 0) {
        ssrc[row0] = p0;
        if (rem > 1) ssrc[row0 + 1] = p1;
        if (rem > 2) ssrc[row0 + 2] = p2;
        if (rem > 3) ssrc[row0 + 3] = p3;
    }
    if (sdst_out) {
        float vl = v2d[lane];
        float q0 = xr0 * vl, q1 = xr1 * vl, q2 = xr2 * vl, q3 = xr3 * vl;
#pragma unroll
        for (int off = 32; off; off >>= 1) {
            q0 += __shfl_xor(q0, off); q1 += __shfl_xor(q1, off);
            q2 += __shfl_xor(q2, off); q3 += __shfl_xor(q3, off);
        }
        if (lane == 0) {
            sdst_out[row0] = q0;
            if (rem > 1) sdst_out[row0 + 1] = q1;
            if (rem > 2) sdst_out[row0 + 2] = q2;
            if (rem > 3) sdst_out[row0 + 3] = q3;
        }
    }
}

// ---- fused: part_hist || proj0 ----
__global__ void hist_proj_kernel(const int* __restrict__ dstA, const int* __restrict__ dstB,
                                 int* __restrict__ cntA, int* __restrict__ cntB,
                                 int ne, int nch, int nbA, int nbB,
                                 const float* __restrict__ x, const float* __restrict__ W,
                                 const float* __restrict__ as_, const float* __restrict__ v2d,
                                 __half* __restrict__ hs, float* __restrict__ ssrc,
                                 float* __restrict__ sdst_out, int n) {
    __shared__ float smem[H * H];
    int blk = blockIdx.x;
    if (blk < 2 * nch) {
        int* h = (int*)smem;
        bool second = blk >= nch;
        const int* dst = second ? dstB : dstA;
        int* cnt = second ? cntB : cntA;
        int nb = second ? nbB : nbA;
        int c = second ? blk - nch : blk;
        int beg = c * CHUNK, end = beg + CHUNK;
        if (end > ne) end = ne;
        int t = threadIdx.x;
        for (int i = t; i < NBMAX; i += 256) h[i] = 0;
        __syncthreads();
        for (int i = beg + t; i < end; i += 256) atomicAdd(&h[dst[i] >> BSHIFT], 1);
        __syncthreads();
        for (int b = t; b < nb; b += 256) cnt[(size_t)b * nch + c] = h[b];
        return;
    }
    proj_body<float>(smem, blk - 2 * nch, x, W, as_, v2d, hs, ssrc, sdst_out, n);
}

__global__ void scan_chunks(int* __restrict__ cntA, int* __restrict__ cntB,
                            int* __restrict__ totA, int* __restrict__ totB,
                            int nch, int nbA) {
    __shared__ int sm[512];
    int b = blockIdx.x;
    bool second = b >= nbA;
    int* cnt = second ? cntB : cntA;
    int* tot = second ? totB : totA;
    if (second) b -= nbA;
    int t = threadIdx.x;
    int v = t < nch ? cnt[(size_t)b * nch + t] : 0;
    sm[t] = v;
    __syncthreads();
    for (int off = 1; off < 512; off <<= 1) {
        int u = t >= off ? sm[t - off] : 0;
        __syncthreads();
        sm[t] += u;
        __syncthreads();
    }
    if (t < nch) cnt[(size_t)b * nch + t] = sm[t] - v;
    if (t == 511) tot[b] = sm[511];
}

__global__ void scan_buckets(const int* __restrict__ totA, const int* __restrict__ totB,
                             int* __restrict__ bstartA, int* __restrict__ bstartB,
                             int nbA, int nbB, int ne) {
    __shared__ int sm[256];
    const int* tot = blockIdx.x ? totB : totA;
    int* bstart = blockIdx.x ? bstartB : bstartA;
    int nb = blockIdx.x ? nbB : nbA;
    int t = threadIdx.x;
    int v = t < nb ? tot[t] : 0;
    sm[t] = v;
    __syncthreads();
    for (int off = 1; off < 256; off <<= 1) {
        int u = t >= off ? sm[t - off] : 0;
        __syncthreads();
        sm[t] += u;
        __syncthreads();
    }
    if (t < nb) bstart[t] = sm[t] - v;
    if (t == 0) bstart[nb] = ne;
}

// ---- fused: part_scatter || proj1 ----
__global__ void scatter_proj_kernel(const int* __restrict__ srcA, const int* __restrict__ dstA,
                                    const int* __restrict__ cntA, const int* __restrict__ bstartA,
                                    unsigned* __restrict__ tmpA,
                                    const int* __restrict__ srcB, const int* __restrict__ dstB,
                                    const int* __restrict__ cntB, const int* __restrict__ bstartB,
                                    unsigned* __restrict__ tmpB,
                                    int ne, int nch, int nbA, int nbB,
                                    const float* __restrict__ x, const float* __restrict__ W,
                                    const float* __restrict__ as_, const float* __restrict__ v2d,
                                    __half* __restrict__ hs, float* __restrict__ ssrc,
                                    float* __restrict__ sdst_out, int n) {
    __shared__ float smem[H * H];
    int blk = blockIdx.x;
    if (blk < 2 * nch) {
        int* cur = (int*)smem;
        bool second = blk >= nch;
        const int* src = second ? srcB : srcA;
        const int* dst = second ? dstB : dstA;
        const int* cnt = second ? cntB : cntA;
        const int* bstart = second ? bstartB : bstartA;
        unsigned* tmp = second ? tmpB : tmpA;
        int nb = second ? nbB : nbA;
        int c = second ? blk - nch : blk;
        int beg = c * CHUNK, end = beg + CHUNK;
        if (end > ne) end = ne;
        int t = threadIdx.x;
        for (int b = t; b < nb; b += 256) cur[b] = bstart[b] + cnt[(size_t)b * nch + c];
        __syncthreads();
        for (int i = beg + t; i < end; i += 256) {
            int d = dst[i];
            int pos = atomicAdd(&cur[d >> BSHIFT], 1);
            unsigned rec = ((unsigned)(d & (BUCKET - 1)) << 17) | (unsigned)src[i];
            tmp[pos] = rec;
        }
        return;
    }
    proj_body<float>(smem, blk - 2 * nch, x, W, as_, v2d, hs, ssrc, sdst_out, n);
}

__global__ void bucket_finalize(const unsigned* __restrict__ tmpA, const int* __restrict__ bstartA,
                                int* __restrict__ rowptrA, int* __restrict__ srcsA,
                                int ndstA, int nbA,
                                const unsigned* __restrict__ tmpB, const int* __restrict__ bstartB,
                                int* __restrict__ rowptrB, int* __restrict__ srcsB,
                                int ndstB) {
    __shared__ int cnt[BUCKET];
    __shared__ int sm[BUCKET];
    __shared__ int cur[BUCKET];
    int b = blockIdx.x;
    bool second = b >= nbA;
    const unsigned* tmp = second ? tmpB : tmpA;
    const int* bstart = second ? bstartB : bstartA;
    int* rowptr = second ? rowptrB : rowptrA;
    int* srcs   = second ? srcsB : srcsA;
    int ndst    = second ? ndstB : ndstA;
    if (second) b -= nbA;

    int t = threadIdx.x;
    int base = bstart[b], endi = bstart[b + 1];
    cnt[t] = 0;
    __syncthreads();
    for (int i = base + t; i < endi; i += 512)
        atomicAdd(&cnt[tmp[i] >> 17], 1);
    __syncthreads();
    int c0 = cnt[t];
    sm[t] = c0;
    __syncthreads();
    for (int off = 1; off < 512; off <<= 1) {
        int u = t >= off ? sm[t - off] : 0;
        __syncthreads();
        sm[t] += u;
        __syncthreads();
    }
    int d0 = b << BSHIFT;
    int e = base + sm[t] - c0;
    cur[t] = e;
    if (d0 + t < ndst) rowptr[d0 + t] = e;
    if (t == 0) {
        int hi = d0 + BUCKET;
        if (hi > ndst) hi = ndst;
        rowptr[hi] = endi;
    }
    __syncthreads();
    for (int i = base + t; i < endi; i += 512) {
        unsigned rec = tmp[i];
        int pos = atomicAdd(&cur[rec >> 17], 1);
        srcs[pos] = (int)(rec & 0x1FFFFu);
    }
}

// ---- 1-node-per-wave general/tiered path (used by gat_mlp and deg>32 fallback) ----
template <int P>
__device__ __forceinline__ float gat_fast(const int* __restrict__ srcs, int beg, int cnt,
                                          const float* __restrict__ ssrc, float sdst,
                                          const __half* __restrict__ hs,
                                          const float* __restrict__ bias, int lane) {
    bool valid = lane < cnt;
    int s_l = valid ? srcs[beg + lane] : 0;
    float ss = valid ? ssrc[s_l] : 0.f;

    const __half* hsl = hs + lane;
    __half hv[P];
#pragma unroll
    for (int k = 0; k < P; ++k) {
        hv[k] = hsl[(size_t)bcasti(s_l, k) * H];
    }

    float sc = ss + sdst;
    sc = sc > 0.f ? sc : 0.2f * sc;
    float ev_l = valid ? __expf(sc) : 0.f;
    float ll = ev_l;
#pragma unroll
    for (int off = 32; off; off >>= 1) ll += __shfl_xor(ll, off);

    float acc0 = 0.f, acc1 = 0.f, acc2 = 0.f, acc3 = 0.f;
    float acc4 = 0.f, acc5 = 0.f, acc6 = 0.f, acc7 = 0.f;
#pragma unroll
    for (int k = 0; k < P; k += 8) {
        acc0 += bcastf(ev_l, k + 0) * __half2float(hv[k + 0]);
        acc1 += bcastf(ev_l, k + 1) * __half2float(hv[k + 1]);
        acc2 += bcastf(ev_l, k + 2) * __half2float(hv[k + 2]);
        acc3 += bcastf(ev_l, k + 3) * __half2float(hv[k + 3]);
        acc4 += bcastf(ev_l, k + 4) * __half2float(hv[k + 4]);
        acc5 += bcastf(ev_l, k + 5) * __half2float(hv[k + 5]);
        acc6 += bcastf(ev_l, k + 6) * __half2float(hv[k + 6]);
        acc7 += bcastf(ev_l, k + 7) * __half2float(hv[k + 7]);
    }
    if constexpr (P == 32) {
        int j = P;
        for (; j + 3 < cnt; j += 4) {
            acc0 += bcastf(ev_l, j + 0) * __half2float(hsl[(size_t)bcasti(s_l, j + 0) * H]);
            acc1 += bcastf(ev_l, j + 1) * __half2float(hsl[(size_t)bcasti(s_l, j + 1) * H]);
            acc2 += bcastf(ev_l, j + 2) * __half2float(hsl[(size_t)bcasti(s_l, j + 2) * H]);
            acc3 += bcastf(ev_l, j + 3) * __half2float(hsl[(size_t)bcasti(s_l, j + 3) * H]);
        }
        for (; j < cnt; ++j)
            acc0 += bcastf(ev_l, j) * __half2float(hsl[(size_t)bcasti(s_l, j) * H]);
    }
    float v = ((acc0 + acc1) + (acc2 + acc3)) + ((acc4 + acc5) + (acc6 + acc7));
    v = v / (ll + 1e-16f) + bias[lane];
    return v > 0.f ? v : 0.f;
}

__device__ __forceinline__ float gat_general(const int* __restrict__ srcs, int beg, int end,
                                             const float* __restrict__ ssrc, float sdst,
                                             const __half* __restrict__ hs,
                                             const float* __restrict__ bias, int lane) {
    const __half* hsl = hs + lane;
    float acc0 = 0.f, acc1 = 0.f;
    float mm = -3.4e38f;
    for (int base = beg; base < end; base += 64) {
        int idx = base + lane;
        if (idx < end) {
            float sc = ssrc[srcs[idx]] + sdst;
            sc = sc > 0.f ? sc : 0.2f * sc;
            mm = fmaxf(mm, sc);
        }
    }
#pragma unroll
    for (int off = 32; off; off >>= 1) mm = fmaxf(mm, __shfl_xor(mm, off));
    float ll = 0.f;
    for (int base = beg; base < end; base += 64) {
        int idx = base + lane;
        int c2 = end - base; if (c2 > 64) c2 = 64;
        int s_l = idx < end ? srcs[idx] : 0;
        float ev_l = 0.f;
        if (idx < end) {
            float sc = ssrc[s_l] + sdst;
            sc = sc > 0.f ? sc : 0.2f * sc;
            ev_l = __expf(sc - mm);
        }
        ll += ev_l;
        int j = 0;
        for (; j + 1 < c2; j += 2) {
            acc0 += bcastf(ev_l, j) * __half2float(hsl[(size_t)bcasti(s_l, j) * H]);
            acc1 += bcastf(ev_l, j + 1) * __half2float(hsl[(size_t)bcasti(s_l, j + 1) * H]);
        }
        if (j < c2)
            acc0 += bcastf(ev_l, j) * __half2float(hsl[(size_t)bcasti(s_l, j) * H]);
    }
#pragma unroll
    for (int off = 32; off; off >>= 1) ll += __shfl_xor(ll, off);
    float v = (acc0 + acc1) / (ll + 1e-16f) + bias[lane];
    return v > 0.f ? v : 0.f;
}

__device__ __forceinline__ float gat_aggregate(const int* __restrict__ rowptr,
                                               const int* __restrict__ srcs,
                                               const float* __restrict__ ssrc,
                                               float sdst,
                                               const __half* __restrict__ hs,
                                               const float* __restrict__ bias,
                                               int wid, int lane) {
    int beg = rowptr[wid], end = rowptr[wid + 1];
    int cnt = end - beg;
    if (cnt <= 16) return gat_fast<16>(srcs, beg, cnt, ssrc, sdst, hs, bias, lane);
    if (cnt <= 64) return gat_fast<32>(srcs, beg, cnt, ssrc, sdst, hs, bias, lane);
    return gat_general(srcs, beg, end, ssrc, sdst, hs, bias, lane);
}

// ---- 2-nodes-per-wave half2 gather fast path ----
// lanes 0-31 = node A (channels 2sub,2sub+1), lanes 32-63 = node B.
// Returns per-lane float2 (2 channels, post-div+bias+relu).
template <int P>
__device__ __forceinline__ float2 gat_pair_fast(const int* __restrict__ srcs,
                                                int r0, int r1, int cnt0, int cnt1,
                                                const float* __restrict__ ssrc,
                                                float sdstA, float sdstB,
                                                const __half* __restrict__ hs,
                                                const float* __restrict__ bias,
                                                int lane) {
    int half = lane >> 5, sub = lane & 31;
    int beg = half ? r1 : r0;
    int cnt = half ? cnt1 : cnt0;
    bool valid = sub < cnt;
    int s_l = valid ? srcs[beg + sub] : 0;
    float ss = valid ? ssrc[s_l] : 0.f;
    float sdst = half ? sdstB : sdstA;

    // prefetch P rows per half (one half2 per lane)
    const __half2* hp = (const __half2*)hs;   // row stride = 32 half2
    __half2 hv[P];
#pragma unroll
    for (int k = 0; k < P; ++k) {
        int sA = bcasti(s_l, k), sB = bcasti(s_l, 32 + k);
        int srow = half ? sB : sA;
        hv[k] = hp[(size_t)srow * 32 + sub];
    }

    float sc = ss + sdst;
    sc = sc > 0.f ? sc : 0.2f * sc;
    float ev_l = valid ? __expf(sc) : 0.f;
    float ll = ev_l;
#pragma unroll
    for (int off = 16; off; off >>= 1) ll += __shfl_xor(ll, off);   // within-half sum

    float ax0 = 0.f, ax1 = 0.f, ax2 = 0.f, ax3 = 0.f;
    float ay0 = 0.f, ay1 = 0.f, ay2 = 0.f, ay3 = 0.f;
#pragma unroll
    for (int k = 0; k < P; k += 4) {
#pragma unroll
        for (int u = 0; u < 4; ++u) {
            float eA = bcastf(ev_l, k + u), eB = bcastf(ev_l, 32 + k + u);
            float e = half ? eB : eA;
            float2 f = __half22float2(hv[k + u]);
            if (u == 0) { ax0 += e * f.x; ay0 += e * f.y; }
            if (u == 1) { ax1 += e * f.x; ay1 += e * f.y; }
            if (u == 2) { ax2 += e * f.x; ay2 += e * f.y; }
            if (u == 3) { ax3 += e * f.x; ay3 += e * f.y; }
        }
    }
    float vx = (ax0 + ax1) + (ax2 + ax3);
    float vy = (ay0 + ay1) + (ay2 + ay3);
    float inv = 1.f / (ll + 1e-16f);
    float2 bv = *(const float2*)(bias + 2 * sub);
    vx = vx * inv + bv.x;
    vy = vy * inv + bv.y;
    vx = vx > 0.f ? vx : 0.f;
    vy = vy > 0.f ? vy : 0.f;
    return make_float2(vx, vy);
}

// gat1: rel1 -> fp16 xiA, 2 nodes/wave
__global__ void gat1_kernel(const int* __restrict__ rp, const int* __restrict__ sr,
                            const float* __restrict__ ssrc, const float* __restrict__ sdstArr,
                            const __half* __restrict__ hs, const float* __restrict__ bias,
                            __half* __restrict__ out, int n) {
    int t = (int)(blockIdx.x * blockDim.x + threadIdx.x);
    int pw = t >> 6, lane = t & 63;
    int wid0 = 2 * pw;
    if (wid0 >= n) return;
    bool has1 = wid0 + 1 < n;
    int r0 = rp[wid0], r1 = rp[wid0 + 1];
    int r2 = has1 ? rp[wid0 + 2] : r1;
    int cnt0 = r1 - r0, cnt1 = r2 - r1;
    int mx = cnt0 > cnt1 ? cnt0 : cnt1;
    int half = lane >> 5, sub = lane & 31;

    if (mx <= 32) {
        float sdstA = sdstArr[wid0];
        float sdstB = has1 ? sdstArr[wid0 + 1] : 0.f;
        float2 v;
        if (mx <= 16) v = gat_pair_fast<16>(sr, r0, r1, cnt0, cnt1, ssrc, sdstA, sdstB, hs, bias, lane);
        else          v = gat_pair_fast<32>(sr, r0, r1, cnt0, cnt1, ssrc, sdstA, sdstB, hs, bias, lane);
        int node = half ? wid0 + 1 : wid0;
        if (!half || has1)
            *(__half2*)(out + (size_t)node * H + 2 * sub) = __float22half2_rn(v);
    } else {
        float v0 = gat_aggregate(rp, sr, ssrc, sdstArr[wid0], hs, bias, wid0, lane);
        out[(size_t)wid0 * H + lane] = __float2half_rn(v0);
        if (has1) {
            float v1 = gat_aggregate(rp, sr, ssrc, sdstArr[wid0 + 1], hs, bias, wid0 + 1, lane);
            out[(size_t)(wid0 + 1) * H + lane] = __float2half_rn(v1);
        }
    }
}

// fused: gat0 (sdst-only, 2 nodes/wave) || proj2
__global__ void gat0_proj_kernel(const int* __restrict__ rp0, const int* __restrict__ sr0,
                                 const float* __restrict__ ssrc0, const float* __restrict__ sdst0,
                                 const __half* __restrict__ hs0, const float* __restrict__ bias0,
                                 const float* __restrict__ v2next, float* __restrict__ sdstNext, int n0,
                                 const __half* __restrict__ xiA, const float* __restrict__ Wsrc2,
                                 const float* __restrict__ as2,
                                 __half* __restrict__ hs2, float* __restrict__ ssrc2, int n1) {
    __shared__ float smem[H * H];
    int npair = (n0 + 1) / 2;
    int nblk0 = (npair + 3) / 4;
    if ((int)blockIdx.x < nblk0) {
        int t = (int)(blockIdx.x * blockDim.x + threadIdx.x);
        int pw = t >> 6, lane = t & 63;
        int wid0 = 2 * pw;
        if (wid0 >= n0) return;
        bool has1 = wid0 + 1 < n0;
        int r0 = rp0[wid0], r1 = rp0[wid0 + 1];
        int r2 = has1 ? rp0[wid0 + 2] : r1;
        int cnt0 = r1 - r0, cnt1 = r2 - r1;
        int mx = cnt0 > cnt1 ? cnt0 : cnt1;
        int half = lane >> 5, sub = lane & 31;

        if (mx <= 32) {
            float sdA = sdst0[wid0];
            float sdB = has1 ? sdst0[wid0 + 1] : 0.f;
            float2 v;
            if (mx <= 16) v = gat_pair_fast<16>(sr0, r0, r1, cnt0, cnt1, ssrc0, sdA, sdB, hs0, bias0, lane);
            else          v = gat_pair_fast<32>(sr0, r0, r1, cnt0, cnt1, ssrc0, sdA, sdB, hs0, bias0, lane);
            float2 w2 = *(const float2*)(v2next + 2 * sub);
            float q = v.x * w2.x + v.y * w2.y;
#pragma unroll
            for (int off = 16; off; off >>= 1) q += __shfl_xor(q, off);
            int node = half ? wid0 + 1 : wid0;
            if (sub == 0 && (!half || has1)) sdstNext[node] = q;
        } else {
            float v0 = gat_aggregate(rp0, sr0, ssrc0, sdst0[wid0], hs0, bias0, wid0, lane);
            float q0 = v0 * v2next[lane];
#pragma unroll
            for (int off = 32; off; off >>= 1) q0 += __shfl_xor(q0, off);
            if (lane == 0) sdstNext[wid0] = q0;
            if (has1) {
                float v1 = gat_aggregate(rp0, sr0, ssrc0, sdst0[wid0 + 1], hs0, bias0, wid0 + 1, lane);
                float q1 = v1 * v2next[lane];
#pragma unroll
                for (int off = 32; off; off >>= 1) q1 += __shfl_xor(q1, off);
                if (lane == 0) sdstNext[wid0 + 1] = q1;
            }
        }
        return;
    }
    proj_body<__half>(smem, blockIdx.x - nblk0, xiA, Wsrc2, as2, nullptr, hs2, ssrc2, nullptr, n1);
}

// final relation: GAT aggregation + fused MLP head (1 node/wave, lane=channel)
__global__ void gat_node_mlp_kernel(const int* __restrict__ rowptr, const int* __restrict__ srcs,
                                    const float* __restrict__ ssrc, const float* __restrict__ sdstArr,
                                    const __half* __restrict__ hs, const float* __restrict__ bias,
                                    const float* __restrict__ w1, const float* __restrict__ b1,
                                    const float* __restrict__ w2, const float* __restrict__ b2,
                                    float* __restrict__ out, int ndst) {
    __shared__ float W1[H * 32];
    __shared__ float W2[32];
    __shared__ float B1[32];
    {
        int t = threadIdx.x;
        for (int i = t; i < H * 32; i += 256) W1[i] = w1[i];
        if (t < 32) { W2[t] = w2[t]; B1[t] = b1[t]; }
        __syncthreads();
    }
    int wid = (int)((blockIdx.x * blockDim.x + threadIdx.x) >> 6);
    int lane = threadIdx.x & 63;
    if (wid >= ndst) return;
    float v = gat_aggregate(rowptr, srcs, ssrc, sdstArr[wid], hs, bias, wid, lane);

    int c = lane & 31;
    int kbase = (lane >> 5) << 5;
    float s = 0.f;
#pragma unroll
    for (int k = 0; k < 32; ++k) s += __shfl(v, kbase + k) * W1[(kbase + k) * 32 + c];
    s += __shfl_xor(s, 32);
    s += B1[c];
    s = s > 0.f ? s : 0.f;
    float q = s * W2[c];
#pragma unroll
    for (int off = 16; off; off >>= 1) q += __shfl_xor(q, off);
    if (lane == 0) out[wid] = q + b2[0];
}

extern "C" void kernel_launch(void* const* d_in, const int* in_sizes, int n_in,
                              void* d_out, int out_size, void* d_ws, size_t ws_size,
                              hipStream_t stream) {
    const float* x_inst  = (const float*)d_in[0];
    const float* x_net   = (const float*)d_in[1];
    const int*   e_i2n   = (const int*)d_in[2];
    const int*   e_n2i   = (const int*)d_in[3];
    const float* W_src   = (const float*)d_in[4];
    const float* W_dst   = (const float*)d_in[5];
    const float* att_src = (const float*)d_in[6];
    const float* att_dst = (const float*)d_in[7];
    const float* bias_g  = (const float*)d_in[8];
    const float* lin1_w  = (const float*)d_in[9];
    const float* lin1_b  = (const float*)d_in[10];
    const float* lin2_w  = (const float*)d_in[11];
    const float* lin2_b  = (const float*)d_in[12];

    const int n_inst = in_sizes[0] / H;
    const int n_net  = in_sizes[1] / H;
    const int ne     = in_sizes[2] / 2;
    const int nmax   = n_inst > n_net ? n_inst : n_net;

    const int nbA = (n_net + BUCKET - 1) >> BSHIFT;
    const int nbB = (n_inst + BUCKET - 1) >> BSHIFT;
    const int nch = (ne + CHUNK - 1) / CHUNK;   // must be <= 512

    float* ws = (float*)d_ws;
    size_t off = 0;
    auto alloc = [&](size_t nelem) {
        off = (off + 3) & ~(size_t)3;
        float* p = ws + off; off += nelem; return p;
    };
    __half* xiA    = (__half*)alloc((size_t)n_inst * H / 2);
    __half* hs0    = (__half*)alloc((size_t)nmax * H / 2);
    __half* hs1    = (__half*)alloc((size_t)nmax * H / 2);
    __half* hs2    = (__half*)alloc((size_t)nmax * H / 2);
    float* ssrc0   = alloc(nmax);
    float* ssrc1   = alloc(nmax);
    float* ssrc2   = alloc(nmax);
    float* sdstA   = alloc(nmax);
    float* sdstB   = alloc(nmax);
    float* sdstC   = alloc(nmax);
    int*   rp_i2n  = (int*)alloc(nmax + 1);
    int*   sr_i2n  = (int*)alloc(ne);
    int*   rp_n2i  = (int*)alloc(nmax + 1);
    int*   sr_n2i  = (int*)alloc(ne);
    unsigned* tmpA = (unsigned*)alloc(ne);
    unsigned* tmpB = (unsigned*)alloc(ne);
    int*   cntA    = (int*)alloc((size_t)NBMAX * nch);
    int*   cntB    = (int*)alloc((size_t)NBMAX * nch);
    int*   totA    = (int*)alloc(NBMAX);
    int*   totB    = (int*)alloc(NBMAX);
    int*   bstartA = (int*)alloc(NBMAX + 1);
    int*   bstartB = (int*)alloc(NBMAX + 1);
    float* v2all   = alloc(3 * H);
    (void)ws_size;

    const int* dstA = e_i2n + ne;   // dst = net
    const int* dstB = e_n2i + ne;   // dst = inst

    wvec3_kernel<<<3, 64, 0, stream>>>(W_dst, att_dst, v2all);

    // hist (A+B) || proj0
    {
        int grid = 2 * nch + (n_inst + 15) / 16;
        hist_proj_kernel<<<grid, 256, 0, stream>>>(dstA, dstB, cntA, cntB, ne, nch, nbA, nbB,
                                                   x_inst, W_src + 0 * H * H, att_src + 0 * H,
                                                   v2all + 1 * H, hs0, ssrc0, sdstB, n_inst);
    }
    scan_chunks<<<nbA + nbB, 512, 0, stream>>>(cntA, cntB, totA, totB, nch, nbA);
    scan_buckets<<<2, 256, 0, stream>>>(totA, totB, bstartA, bstartB, nbA, nbB, ne);
    // scatter (A+B) || proj1
    {
        int grid = 2 * nch + (n_net + 15) / 16;
        scatter_proj_kernel<<<grid, 256, 0, stream>>>(e_i2n, dstA, cntA, bstartA, tmpA,
                                                      e_n2i, dstB, cntB, bstartB, tmpB,
                                                      ne, nch, nbA, nbB,
                                                      x_net, W_src + 1 * H * H, att_src + 1 * H,
                                                      v2all + 0 * H, hs1, ssrc1, sdstA, n_net);
    }
    bucket_finalize<<<nbA + nbB, 512, 0, stream>>>(tmpA, bstartA, rp_i2n, sr_i2n, n_net, nbA,
                                                   tmpB, bstartB, rp_n2i, sr_n2i, n_inst);

    // gat1 (rel1 -> fp16 xiA, 2 nodes/wave): critical path first
    {
        int npair = (n_inst + 1) / 2;
        gat1_kernel<<<(npair + 3) / 4, 256, 0, stream>>>(rp_n2i, sr_n2i, ssrc1, sdstB,
                                                         hs1, bias_g + 1 * H, xiA, n_inst);
    }
    // gat0 (2 nodes/wave, sdst-only -> sdstC) || proj2
    {
        int npair0 = (n_net + 1) / 2;
        int grid = (npair0 + 3) / 4 + (n_inst + 15) / 16;
        gat0_proj_kernel<<<grid, 256, 0, stream>>>(rp_i2n, sr_i2n, ssrc0, sdstA, hs0,
                                                   bias_g + 0 * H, v2all + 2 * H, sdstC, n_net,
                                                   xiA, W_src + 2 * H * H, att_src + 2 * H,
                                                   hs2, ssrc2, n_inst);
    }
    // gat2 (rel2) + MLP head -> d_out
    gat_node_mlp_kernel<<<(n_net + 3) / 4, 256, 0, stream>>>(rp_i2n, sr_i2n, ssrc2, sdstC,
                                                             hs2, bias_g + 2 * H,
                                                             lin1_w, lin1_b, lin2_w, lin2_b,
                                                             (float*)d_out, n_net);
}